// Round 3
// baseline (200.527 us; speedup 1.0000x reference)
//
#include <hip/hip_runtime.h>

// ImplicitFunction MLP via fp16 MFMA (v_mfma_f32_32x32x16_f16), round 7.
// Round-7 changes (latency-overlap attack; pipes were only 82% busy combined,
// waves serialize [MFMA -> D-latency -> packfr -> MFMA]):
//  - Two-ntile software pipeline: tile-0's MFMA chain overlaps tile-1's
//    packfr VALU and vice versa (independent data, zero extra registers).
//    Order per layer: MFMA(nt0) | pack(nt1,prev) | MFMA(nt1) | pack(nt0,cur).
//  - wo A-frags compacted to broadcast form [s:4][h:2] (4096B -> 128B): all
//    lanes in a half read the same 16B (LDS broadcast). LDS back to 53.2KB.
//  - bo folded into output-MFMA C-operand (boC, all 16 slots = bo): kills
//    zero-init movs + final scalar adds.
//  - Layer loop fully unrolled: all ds_reads become base+imm (W image fits
//    16-bit offset), scheduler can hoist next layer's W reads under MFMA.
//
// Carried: K-permuted weights (exchange-free layer transition), bias in MFMA
// C-operand, packed-fp16 lrelu, activations scaled 1/64, 64 pts/wave,
// MFMA output layer, 512-thread blocks, __launch_bounds__(512,4), setprio
// around MFMA clusters.
//
// Layouts (gfx950, 32x32x16):
//   A/B frag: lane (i=lane&31, h=lane>>5) holds k = 8h+j, j=0..7
//   C/D:      col n = lane&31, row m = (r&3) + 8*(r>>2) + 4h, r=0..15
//   k-slot:   feat(s,h,j) = 16s + 8*(j>>2) + 4h + (j&3)

typedef _Float16 half8 __attribute__((ext_vector_type(8)));
typedef _Float16 half2v __attribute__((ext_vector_type(2)));
typedef float floatx16 __attribute__((ext_vector_type(16)));
typedef int int4v __attribute__((ext_vector_type(4)));

#define N_HID 6
// ws / LDS byte offsets (single contiguous image, staged wholesale)
#define OFF_A 0        // hidden W frags [l:6][t:2][s:4][lane:64][j:8] fp16 = 49152
#define OFF_B 49152    // layer0 A frags [t:2][lane:64][j:8] fp16          = 2048
#define OFF_C 51200    // bias/64 fp32, C-layout [l:7][h:2][t:2][r:16]     = 1792
#define OFF_D 52992    // wo*so*64 fp16 broadcast A-frags [s:4][h:2][j:8]  = 128
#define OFF_E 53120    // bo fp32 broadcast C operand [r:16]               = 64
#define IMG_BYTES 53184
#define SETUP_TOTAL (24576 + 1024 + 448 + 64 + 16)

__global__ __launch_bounds__(256) void setup_weights(
    const float* __restrict__ w0, const float* __restrict__ s0, const float* __restrict__ b0,
    const float* __restrict__ wh, const float* __restrict__ sh, const float* __restrict__ bh,
    const float* __restrict__ wo, const float* __restrict__ so, const float* __restrict__ bo,
    unsigned char* __restrict__ ws)
{
    int i = blockIdx.x * 256 + threadIdx.x;
    if (i < 24576) {
        // hidden W frags with K-permutation baked in:
        // A[m][kslot(s,h,j)] = wh[l][feat][m] * sh[l][m], feat = 16s+8*(j>>2)+4h+(j&3)
        int j = i & 7, lane = (i >> 3) & 63, s = (i >> 9) & 3, t = (i >> 11) & 1, l = i >> 12;
        int m = 32 * t + (lane & 31);
        int h = lane >> 5;
        int feat = 16 * s + 8 * (j >> 2) + 4 * h + (j & 3);
        ((_Float16*)(ws + OFF_A))[i] = (_Float16)(wh[(l * 64 + feat) * 64 + m] * sh[l * 64 + m]);
    } else if (i < 24576 + 1024) {
        // layer-0 A frags (standard k order; B built from raw points)
        int i2 = i - 24576;
        int j = i2 & 7, lane = (i2 >> 3) & 63, t = i2 >> 9;
        int m = 32 * t + (lane & 31);
        int k = 8 * (lane >> 5) + j;
        float v = (k < 3) ? w0[k * 64 + m] * s0[m] * 0.015625f : 0.f;
        ((_Float16*)(ws + OFF_B))[i2] = (_Float16)v;
    } else if (i < 24576 + 1024 + 448) {
        // biases/64 in C layout
        int i2 = i - 24576 - 1024;
        int r = i2 & 15, t = (i2 >> 4) & 1, h = (i2 >> 5) & 1, l = i2 >> 6;
        int feat = 32 * t + (r & 3) + 8 * ((r >> 2) & 3) + 4 * h;
        float bv = (l == 0) ? b0[feat] : bh[(l - 1) * 64 + feat];
        ((float*)(ws + OFF_C))[i2] = bv * 0.015625f;
    } else if (i < 24576 + 1024 + 448 + 64) {
        // wo*so*64 fp16, broadcast A-frag values [s][h][j] (same for all rows)
        int i2 = i - (24576 + 1024 + 448);
        int j = i2 & 7, hh = (i2 >> 3) & 1, s = i2 >> 4;
        int feat = 16 * s + 8 * (j >> 2) + 4 * hh + (j & 3);
        ((_Float16*)(ws + OFF_D))[i2] = (_Float16)(wo[feat] * so[0] * 64.f);
    } else if (i < SETUP_TOTAL) {
        // bo broadcast into all 16 C slots
        ((float*)(ws + OFF_E))[i - (24576 + 1024 + 448 + 64)] = bo[0];
    }
}

static __device__ __forceinline__ int pkrtz(float a, float b) {
    auto hh = __builtin_amdgcn_cvt_pkrtz(a, b);  // v2f16, RTZ pack
    int r;
    __builtin_memcpy(&r, &hh, 4);
    return r;
}

// packed-fp16 leaky relu on a pair: max(u, 0.2*u) -> v_pk_mul_f16 + v_pk_max_f16
static __device__ __forceinline__ int lrelu2(int v) {
    half2v u;
    __builtin_memcpy(&u, &v, 4);
    half2v w = u * (_Float16)0.2f;
    half2v r = __builtin_elementwise_max(u, w);
    int o;
    __builtin_memcpy(&o, &r, 4);
    return o;
}

static __device__ __forceinline__ half8 as_h8(int4v v) {
    half8 r;
    __builtin_memcpy(&r, &v, 16);
    return r;
}

static __device__ __forceinline__ floatx16 mfma16(half8 a, half8 b, floatx16 c) {
    return __builtin_amdgcn_mfma_f32_32x32x16_f16(a, b, c, 0, 0, 0);
}

// acc pair -> packed+lrelu B-frags (constant indices after inlining)
static __device__ __forceinline__ void packfr2(const floatx16 a[2], int4v f[4]) {
#pragma unroll
    for (int t = 0; t < 2; ++t)
#pragma unroll
        for (int rp = 0; rp < 8; ++rp) {
            int v = pkrtz(a[t][2 * rp], a[t][2 * rp + 1]);
            int idx = 8 * t + rp;
            f[idx >> 2][idx & 3] = lrelu2(v);
        }
}

__global__ __launch_bounds__(512, 4) void mlp_mfma(
    const float* __restrict__ points,
    const unsigned char* __restrict__ ws,
    float* __restrict__ out, int n)
{
    __shared__ __align__(16) unsigned char lds[IMG_BYTES];

    // stage full weight image to LDS (53184 B = 3324 * 16; 512 threads)
    {
        const uint4* src = (const uint4*)ws;
        uint4* dst = (uint4*)lds;
#pragma unroll
        for (int i = 0; i < 6; ++i) {
            int idx = threadIdx.x + 512 * i;
            dst[idx] = src[idx];
        }
        if (threadIdx.x < 252) {
            int idx = 3072 + threadIdx.x;
            dst[idx] = src[idx];
        }
    }
    __syncthreads();

    const int lane = threadIdx.x & 63;
    const int wv = threadIdx.x >> 6;   // 0..7 (8 waves/block)
    const int p = lane & 31;
    const int h = lane >> 5;
    const int base = (blockIdx.x * 8 + wv) * 64;
    const int pt0 = base + p, pt1 = base + 32 + p;
    const int pl0 = min(pt0, n - 1), pl1 = min(pt1, n - 1);

    const half8* Wf = (const half8*)(lds + OFF_A);          // [l][t][s][lane]
    const half8* A0 = (const half8*)(lds + OFF_B);          // [t][lane]
    const floatx16* biasC = (const floatx16*)(lds + OFF_C); // [(l*2+h)*2+t]
    const half8* woD = (const half8*)(lds + OFF_D);         // [s*2+h] broadcast
    const floatx16* boC = (const floatx16*)(lds + OFF_E);   // [0] broadcast

    floatx16 acc0[2], acc1[2];   // [mtile] per n-tile
    int4v frv0[4], frv1[4];      // packed activations per n-tile, [kstep]

    // ---- layer 0 ----
    {
        int4v z4 = {0, 0, 0, 0};
        int4v b0v = z4, b1v = z4;
        if (h == 0) {
            b0v[0] = pkrtz(points[3 * pl0 + 0], points[3 * pl0 + 1]);
            b0v[1] = pkrtz(points[3 * pl0 + 2], 0.f);
            b1v[0] = pkrtz(points[3 * pl1 + 0], points[3 * pl1 + 1]);
            b1v[1] = pkrtz(points[3 * pl1 + 2], 0.f);
        }
        floatx16 c0 = biasC[h * 2 + 0];   // l = 0
        floatx16 c1 = biasC[h * 2 + 1];
        half8 a0 = A0[lane], a1 = A0[64 + lane];
        __builtin_amdgcn_s_setprio(1);
        acc0[0] = mfma16(a0, as_h8(b0v), c0);
        acc0[1] = mfma16(a1, as_h8(b0v), c1);
        acc1[0] = mfma16(a0, as_h8(b1v), c0);
        acc1[1] = mfma16(a1, as_h8(b1v), c1);
        __builtin_amdgcn_s_setprio(0);
    }

    // prologue: only nt0 packed; nt1's pack is pipelined into the loop
    packfr2(acc0, frv0);

    // ---- 6 hidden layers, two-ntile software pipeline ----
#pragma unroll
    for (int l = 0; l < N_HID; ++l) {
        const half8* wl = Wf + l * 512 + lane;  // + t*256 + s*64
        floatx16 c0 = biasC[((l + 1) * 2 + h) * 2 + 0];
        floatx16 c1 = biasC[((l + 1) * 2 + h) * 2 + 1];

        // MFMA group nt0 (consumes frv0 = act of prev layer)
        __builtin_amdgcn_s_setprio(1);
        acc0[0] = mfma16(wl[0],   as_h8(frv0[0]), c0);
        acc0[1] = mfma16(wl[256], as_h8(frv0[0]), c1);
#pragma unroll
        for (int s = 1; s < 4; ++s) {
            acc0[0] = mfma16(wl[s * 64],       as_h8(frv0[s]), acc0[0]);
            acc0[1] = mfma16(wl[256 + s * 64], as_h8(frv0[s]), acc0[1]);
        }
        __builtin_amdgcn_s_setprio(0);

        // pack nt1 from PREVIOUS layer's acc1 — independent of nt0 group above
        packfr2(acc1, frv1);

        // MFMA group nt1
        __builtin_amdgcn_s_setprio(1);
        acc1[0] = mfma16(wl[0],   as_h8(frv1[0]), c0);
        acc1[1] = mfma16(wl[256], as_h8(frv1[0]), c1);
#pragma unroll
        for (int s = 1; s < 4; ++s) {
            acc1[0] = mfma16(wl[s * 64],       as_h8(frv1[s]), acc1[0]);
            acc1[1] = mfma16(wl[256 + s * 64], as_h8(frv1[s]), acc1[1]);
        }
        __builtin_amdgcn_s_setprio(0);

        // pack nt0 from THIS layer's acc0 — independent of nt1 group above
        packfr2(acc0, frv0);
    }

    // ---- output layer on the MFMA pipe (bo pre-folded into C) ----
    // woD rows are all wo (broadcast): any D element of the chain = output.
    {
        floatx16 co = boC[0];
        __builtin_amdgcn_s_setprio(1);
        floatx16 o0 = mfma16(woD[0 * 2 + h], as_h8(frv0[0]), co);
#pragma unroll
        for (int s = 1; s < 4; ++s)
            o0 = mfma16(woD[s * 2 + h], as_h8(frv0[s]), o0);
        __builtin_amdgcn_s_setprio(0);

        packfr2(acc1, frv1);   // act of last hidden for nt1, overlaps o0 chain

        __builtin_amdgcn_s_setprio(1);
        floatx16 o1 = mfma16(woD[0 * 2 + h], as_h8(frv1[0]), co);
#pragma unroll
        for (int s = 1; s < 4; ++s)
            o1 = mfma16(woD[s * 2 + h], as_h8(frv1[s]), o1);
        __builtin_amdgcn_s_setprio(0);

        if (h == 0) {
            if (pt0 < n) out[pt0] = o0[0];
            if (pt1 < n) out[pt1] = o1[0];
        }
    }
}

extern "C" void kernel_launch(void* const* d_in, const int* in_sizes, int n_in,
                              void* d_out, int out_size, void* d_ws, size_t ws_size,
                              hipStream_t stream) {
    const float* points = (const float*)d_in[0];
    const float* w0     = (const float*)d_in[1];
    const float* s0     = (const float*)d_in[2];
    const float* b0     = (const float*)d_in[3];
    const float* wh     = (const float*)d_in[4];
    const float* sh     = (const float*)d_in[5];
    const float* bh     = (const float*)d_in[6];
    const float* wo     = (const float*)d_in[7];
    const float* so     = (const float*)d_in[8];
    const float* bo     = (const float*)d_in[9];

    const int n = in_sizes[0] / 3;

    setup_weights<<<(SETUP_TOTAL + 255) / 256, 256, 0, stream>>>(
        w0, s0, b0, wh, sh, bh, wo, so, bo, (unsigned char*)d_ws);

    const int grid = (n + 511) / 512;  // 512 points per block (8 waves x 64)
    mlp_mfma<<<grid, 512, 0, stream>>>(
        points, (const unsigned char*)d_ws, (float*)d_out, n);
}

// Round 4
// 136.901 us; speedup vs baseline: 1.4648x; 1.4648x over previous
//
#include <hip/hip_runtime.h>

// ImplicitFunction MLP via fp16 MFMA (v_mfma_f32_32x32x16_f16), round 8.
// Round-8 changes (register-pressure / AGPR-copy attack):
//  - Round-7's two-tile pipeline SPILLED (WRITE_SIZE 4 MB -> 241 MB scratch):
//    reverted to the round-5 structure (rolled layer loop, fp32 epilogue).
//  - 1 n-tile (32 points) per wave instead of 2: live state ~100 regs < the
//    128-reg __launch_bounds__(512,4) budget. Theory: round-5's measured
//    ~2190 VALU inst/wave vs ~900 in source = AGPR<->VGPR copy traffic
//    (acc in AGPRs at 56 arch VGPRs: 64 accvgpr_reads/pack + 32 writes/layer
//    for bias C). With headroom, the allocator keeps acc in arch VGPRs and
//    the copies vanish. Wave count doubles -> more TLP for latency hiding.
//
// Carried: K-permuted weights (exchange-free layer transition), bias in MFMA
// C-operand, packed-fp16 lrelu, activations scaled 1/64, 512-thread blocks,
// 53248-B LDS image (3 blocks/CU boundary), setprio around MFMA clusters.
//
// Layouts (gfx950, 32x32x16):
//   A/B frag: lane (i=lane&31, h=lane>>5) holds k = 8h+j, j=0..7
//   C/D:      col n = lane&31, row m = (r&3) + 8*(r>>2) + 4h, r=0..15
//   k-slot:   feat(s,h,j) = 16s + 8*(j>>2) + 4h + (j&3)

typedef _Float16 half8 __attribute__((ext_vector_type(8)));
typedef _Float16 half2v __attribute__((ext_vector_type(2)));
typedef float floatx16 __attribute__((ext_vector_type(16)));
typedef int int4v __attribute__((ext_vector_type(4)));

#define N_HID 6
// ws / LDS byte offsets (single contiguous image, staged wholesale)
#define OFF_A 0        // hidden W frags [l:6][t:2][s:4][lane:64][j:8] fp16 = 49152
#define OFF_B 49152    // layer0 A frags [t:2][lane:64][j:8] fp16          = 2048
#define OFF_C 51200    // bias/64 fp32, C-layout [l:7][h:2][t:2][r:16]     = 1792
#define OFF_D 52992    // wo*so*64 fp32, C-layout [h:2][t:2][r:16]         = 256
#define IMG_BYTES 53248
#define SETUP_TOTAL (24576 + 1024 + 448 + 64)

__global__ __launch_bounds__(256) void setup_weights(
    const float* __restrict__ w0, const float* __restrict__ s0, const float* __restrict__ b0,
    const float* __restrict__ wh, const float* __restrict__ sh, const float* __restrict__ bh,
    const float* __restrict__ wo, const float* __restrict__ so,
    unsigned char* __restrict__ ws)
{
    int i = blockIdx.x * 256 + threadIdx.x;
    if (i < 24576) {
        // hidden W frags with K-permutation baked in:
        // A[m][kslot(s,h,j)] = wh[l][feat][m] * sh[l][m], feat = 16s+8*(j>>2)+4h+(j&3)
        int j = i & 7, lane = (i >> 3) & 63, s = (i >> 9) & 3, t = (i >> 11) & 1, l = i >> 12;
        int m = 32 * t + (lane & 31);
        int h = lane >> 5;
        int feat = 16 * s + 8 * (j >> 2) + 4 * h + (j & 3);
        ((_Float16*)(ws + OFF_A))[i] = (_Float16)(wh[(l * 64 + feat) * 64 + m] * sh[l * 64 + m]);
    } else if (i < 24576 + 1024) {
        // layer-0 A frags (standard k order; B built from raw points)
        int i2 = i - 24576;
        int j = i2 & 7, lane = (i2 >> 3) & 63, t = i2 >> 9;
        int m = 32 * t + (lane & 31);
        int k = 8 * (lane >> 5) + j;
        float v = (k < 3) ? w0[k * 64 + m] * s0[m] * 0.015625f : 0.f;
        ((_Float16*)(ws + OFF_B))[i2] = (_Float16)v;
    } else if (i < 24576 + 1024 + 448) {
        // biases/64 in C layout
        int i2 = i - 24576 - 1024;
        int r = i2 & 15, t = (i2 >> 4) & 1, h = (i2 >> 5) & 1, l = i2 >> 6;
        int feat = 32 * t + (r & 3) + 8 * ((r >> 2) & 3) + 4 * h;
        float bv = (l == 0) ? b0[feat] : bh[(l - 1) * 64 + feat];
        ((float*)(ws + OFF_C))[i2] = bv * 0.015625f;
    } else if (i < SETUP_TOTAL) {
        // wo*so*64 in C layout
        int i2 = i - 24576 - 1024 - 448;
        int r = i2 & 15, t = (i2 >> 4) & 1, h = i2 >> 5;
        int feat = 32 * t + (r & 3) + 8 * ((r >> 2) & 3) + 4 * h;
        ((float*)(ws + OFF_D))[i2] = wo[feat] * so[0] * 64.f;
    }
}

static __device__ __forceinline__ int pkrtz(float a, float b) {
    auto hh = __builtin_amdgcn_cvt_pkrtz(a, b);  // v2f16, RTZ pack
    int r;
    __builtin_memcpy(&r, &hh, 4);
    return r;
}

// packed-fp16 leaky relu on a pair: max(u, 0.2*u) -> v_pk_mul_f16 + v_pk_max_f16
static __device__ __forceinline__ int lrelu2(int v) {
    half2v u;
    __builtin_memcpy(&u, &v, 4);
    half2v w = u * (_Float16)0.2f;
    half2v r = __builtin_elementwise_max(u, w);
    int o;
    __builtin_memcpy(&o, &r, 4);
    return o;
}

static __device__ __forceinline__ half8 as_h8(int4v v) {
    half8 r;
    __builtin_memcpy(&r, &v, 16);
    return r;
}

static __device__ __forceinline__ floatx16 mfma16(half8 a, half8 b, floatx16 c) {
    return __builtin_amdgcn_mfma_f32_32x32x16_f16(a, b, c, 0, 0, 0);
}

__global__ __launch_bounds__(512, 4) void mlp_mfma(
    const float* __restrict__ points,
    const unsigned char* __restrict__ ws,
    const float* __restrict__ bo,
    float* __restrict__ out, int n)
{
    __shared__ __align__(16) unsigned char lds[IMG_BYTES];

    // stage full weight image to LDS (53248 B = 3328 * 16; 512 threads)
    {
        const uint4* src = (const uint4*)ws;
        uint4* dst = (uint4*)lds;
#pragma unroll
        for (int i = 0; i < 6; ++i) {
            int idx = threadIdx.x + 512 * i;
            dst[idx] = src[idx];
        }
        if (threadIdx.x < 256) {
            int idx = 3072 + threadIdx.x;
            dst[idx] = src[idx];
        }
    }
    __syncthreads();

    const int lane = threadIdx.x & 63;
    const int wv = threadIdx.x >> 6;   // 0..7 (8 waves/block)
    const int p = lane & 31;
    const int h = lane >> 5;
    const int pt = (blockIdx.x * 8 + wv) * 32 + p;   // 32 points per wave
    const int pl = min(pt, n - 1);

    const half8* Wf = (const half8*)(lds + OFF_A);          // [l][t][s][lane]
    const half8* A0 = (const half8*)(lds + OFF_B);          // [t][lane]
    const floatx16* biasC = (const floatx16*)(lds + OFF_C); // [(l*2+h)*2+t]
    const floatx16* woC = (const floatx16*)(lds + OFF_D);   // [h*2+t]

    floatx16 acc[2];   // [mtile]
    int4v frv[4];      // packed activations, [kstep] = next B-frag

    // ---- layer 0 ----
    {
        int4v bv = {0, 0, 0, 0};
        if (h == 0) {
            bv[0] = pkrtz(points[3 * pl + 0], points[3 * pl + 1]);
            bv[1] = pkrtz(points[3 * pl + 2], 0.f);
        }
        floatx16 c0 = biasC[h * 2 + 0];   // l = 0
        floatx16 c1 = biasC[h * 2 + 1];
        __builtin_amdgcn_s_setprio(1);
        acc[0] = mfma16(A0[lane], as_h8(bv), c0);
        acc[1] = mfma16(A0[64 + lane], as_h8(bv), c1);
        __builtin_amdgcn_s_setprio(0);
    }

    // pack + lrelu -> frv (also the next layer's B-frags, exchange-free)
    auto packfr = [&]() {
#pragma unroll
        for (int t = 0; t < 2; ++t)
#pragma unroll
            for (int rp = 0; rp < 8; ++rp) {
                int v = pkrtz(acc[t][2 * rp], acc[t][2 * rp + 1]);
                int idx = 8 * t + rp;
                frv[idx >> 2][idx & 3] = lrelu2(v);
            }
    };
    packfr();

    // ---- 6 hidden layers ----
    for (int l = 0; l < N_HID; ++l) {
        const floatx16 c0 = biasC[((l + 1) * 2 + h) * 2 + 0];
        const floatx16 c1 = biasC[((l + 1) * 2 + h) * 2 + 1];
        const half8* wl = Wf + l * 512 + lane;  // + t*256 + s*64
        __builtin_amdgcn_s_setprio(1);
        acc[0] = mfma16(wl[0],   as_h8(frv[0]), c0);
        acc[1] = mfma16(wl[256], as_h8(frv[0]), c1);
#pragma unroll
        for (int s = 1; s < 4; ++s) {
            acc[0] = mfma16(wl[s * 64],       as_h8(frv[s]), acc[0]);
            acc[1] = mfma16(wl[256 + s * 64], as_h8(frv[s]), acc[1]);
        }
        __builtin_amdgcn_s_setprio(0);
        if (l < N_HID - 1) packfr();
    }

    // ---- output layer: fp32 lrelu + dot with wo (C-layout), cross-half reduce ----
    {
        floatx16 wo0 = woC[h * 2 + 0];
        floatx16 wo1 = woC[h * 2 + 1];
        float part = 0.f;
#pragma unroll
        for (int r = 0; r < 16; ++r) {
            float u;
            u = acc[0][r]; part = fmaf(fmaxf(u, 0.2f * u), wo0[r], part);
            u = acc[1][r]; part = fmaf(fmaxf(u, 0.2f * u), wo1[r], part);
        }
        part += __shfl_xor(part, 32);
        if (h == 0 && pt < n) out[pt] = part + bo[0];
    }
}

extern "C" void kernel_launch(void* const* d_in, const int* in_sizes, int n_in,
                              void* d_out, int out_size, void* d_ws, size_t ws_size,
                              hipStream_t stream) {
    const float* points = (const float*)d_in[0];
    const float* w0     = (const float*)d_in[1];
    const float* s0     = (const float*)d_in[2];
    const float* b0     = (const float*)d_in[3];
    const float* wh     = (const float*)d_in[4];
    const float* sh     = (const float*)d_in[5];
    const float* bh     = (const float*)d_in[6];
    const float* wo     = (const float*)d_in[7];
    const float* so     = (const float*)d_in[8];
    const float* bo     = (const float*)d_in[9];

    const int n = in_sizes[0] / 3;

    setup_weights<<<(SETUP_TOTAL + 255) / 256, 256, 0, stream>>>(
        w0, s0, b0, wh, sh, bh, wo, so, (unsigned char*)d_ws);

    const int grid = (n + 255) / 256;  // 256 points per block (8 waves x 32)
    mlp_mfma<<<grid, 512, 0, stream>>>(
        points, (const unsigned char*)d_ws, bo, (float*)d_out, n);
}

// Round 6
// 136.694 us; speedup vs baseline: 1.4670x; 1.0015x over previous
//
#include <hip/hip_runtime.h>

// ImplicitFunction MLP via fp16 MFMA (v_mfma_f32_32x32x16_f16), round 10.
// Round-10 change: round-9's inline-asm VGPR-form MFMA NaN'd because inline
// asm is opaque to LLVM's MFMA hazard recognizer — CDNA requires SOFTWARE
// wait states between an MFMA D-write and later VALU reads of those regs
// (and a short wait between VALU writes and MFMA reads). Builtins get these
// nops inserted automatically; asm doesn't. Fix: hazard fences expressed as
// DATA dependencies (asm "+v" on the exact registers), so the scheduler
// cannot move them:
//   mfma_fence(acc0,acc1): s_nop 7 x4 (32 cy >= 16-pass worst case) after
//     each MFMA cluster, tied to both accumulators.
//   valu_fence(frv)/: s_nop 3 before each cluster, tied to the packed
//     activations (covers VALU-write -> MFMA-read).
// Goal unchanged from round 9: acc in arch VGPRs -> zero v_accvgpr_read/
// write traffic (~700 of ~1200 VALU inst/wave in round 8).
//
// Carried from round 8: 1 n-tile (32 pts) per wave, rolled layer loop, fp32
// epilogue, K-permuted weights, bias in MFMA C-operand, packed-fp16 lrelu,
// activations scaled 1/64, 512-thread blocks, 53248-B LDS image,
// __launch_bounds__(512,4), setprio around MFMA clusters.
//
// Layouts (gfx950, 32x32x16):
//   A/B frag: lane (i=lane&31, h=lane>>5) holds k = 8h+j, j=0..7
//   C/D:      col n = lane&31, row m = (r&3) + 8*(r>>2) + 4h, r=0..15
//   k-slot:   feat(s,h,j) = 16s + 8*(j>>2) + 4h + (j&3)

typedef _Float16 half8 __attribute__((ext_vector_type(8)));
typedef _Float16 half2v __attribute__((ext_vector_type(2)));
typedef float floatx16 __attribute__((ext_vector_type(16)));
typedef int int4v __attribute__((ext_vector_type(4)));

#define N_HID 6
// ws / LDS byte offsets (single contiguous image, staged wholesale)
#define OFF_A 0        // hidden W frags [l:6][t:2][s:4][lane:64][j:8] fp16 = 49152
#define OFF_B 49152    // layer0 A frags [t:2][lane:64][j:8] fp16          = 2048
#define OFF_C 51200    // bias/64 fp32, C-layout [l:7][h:2][t:2][r:16]     = 1792
#define OFF_D 52992    // wo*so*64 fp32, C-layout [h:2][t:2][r:16]         = 256
#define IMG_BYTES 53248
#define SETUP_TOTAL (24576 + 1024 + 448 + 64)

__global__ __launch_bounds__(256) void setup_weights(
    const float* __restrict__ w0, const float* __restrict__ s0, const float* __restrict__ b0,
    const float* __restrict__ wh, const float* __restrict__ sh, const float* __restrict__ bh,
    const float* __restrict__ wo, const float* __restrict__ so,
    unsigned char* __restrict__ ws)
{
    int i = blockIdx.x * 256 + threadIdx.x;
    if (i < 24576) {
        // hidden W frags with K-permutation baked in:
        // A[m][kslot(s,h,j)] = wh[l][feat][m] * sh[l][m], feat = 16s+8*(j>>2)+4h+(j&3)
        int j = i & 7, lane = (i >> 3) & 63, s = (i >> 9) & 3, t = (i >> 11) & 1, l = i >> 12;
        int m = 32 * t + (lane & 31);
        int h = lane >> 5;
        int feat = 16 * s + 8 * (j >> 2) + 4 * h + (j & 3);
        ((_Float16*)(ws + OFF_A))[i] = (_Float16)(wh[(l * 64 + feat) * 64 + m] * sh[l * 64 + m]);
    } else if (i < 24576 + 1024) {
        // layer-0 A frags (standard k order; B built from raw points)
        int i2 = i - 24576;
        int j = i2 & 7, lane = (i2 >> 3) & 63, t = i2 >> 9;
        int m = 32 * t + (lane & 31);
        int k = 8 * (lane >> 5) + j;
        float v = (k < 3) ? w0[k * 64 + m] * s0[m] * 0.015625f : 0.f;
        ((_Float16*)(ws + OFF_B))[i2] = (_Float16)v;
    } else if (i < 24576 + 1024 + 448) {
        // biases/64 in C layout
        int i2 = i - 24576 - 1024;
        int r = i2 & 15, t = (i2 >> 4) & 1, h = (i2 >> 5) & 1, l = i2 >> 6;
        int feat = 32 * t + (r & 3) + 8 * ((r >> 2) & 3) + 4 * h;
        float bv = (l == 0) ? b0[feat] : bh[(l - 1) * 64 + feat];
        ((float*)(ws + OFF_C))[i2] = bv * 0.015625f;
    } else if (i < SETUP_TOTAL) {
        // wo*so*64 in C layout
        int i2 = i - 24576 - 1024 - 448;
        int r = i2 & 15, t = (i2 >> 4) & 1, h = i2 >> 5;
        int feat = 32 * t + (r & 3) + 8 * ((r >> 2) & 3) + 4 * h;
        ((float*)(ws + OFF_D))[i2] = wo[feat] * so[0] * 64.f;
    }
}

static __device__ __forceinline__ int pkrtz(float a, float b) {
    auto hh = __builtin_amdgcn_cvt_pkrtz(a, b);  // v2f16, RTZ pack
    int r;
    __builtin_memcpy(&r, &hh, 4);
    return r;
}

// packed-fp16 leaky relu on a pair: max(u, 0.2*u) -> v_pk_mul_f16 + v_pk_max_f16
static __device__ __forceinline__ int lrelu2(int v) {
    half2v u;
    __builtin_memcpy(&u, &v, 4);
    half2v w = u * (_Float16)0.2f;
    half2v r = __builtin_elementwise_max(u, w);
    int o;
    __builtin_memcpy(&o, &r, 4);
    return o;
}

static __device__ __forceinline__ half8 as_h8(int4v v) {
    half8 r;
    __builtin_memcpy(&r, &v, 16);
    return r;
}

// VGPR-form MFMA (inline asm). init: fresh D (earlyclobber keeps D off A/B/C);
// acc: D tied to C (other inputs get distinct regs).
static __device__ __forceinline__ floatx16 mfma_init(half8 a, half8 b, floatx16 c) {
    floatx16 d;
    asm("v_mfma_f32_32x32x16_f16 %0, %1, %2, %3"
        : "=&v"(d) : "v"(a), "v"(b), "v"(c));
    return d;
}
static __device__ __forceinline__ void mfma_acc(floatx16& d, half8 a, half8 b) {
    asm("v_mfma_f32_32x32x16_f16 %0, %1, %2, %0"
        : "+v"(d) : "v"(a), "v"(b));
}

// Hazard fences as data dependencies (scheduler cannot move them off the regs):
// MFMA D-write -> VALU read of acc needs up to ~19 waits (16-pass class); 32 here.
static __device__ __forceinline__ void mfma_fence(floatx16& d0, floatx16& d1) {
    asm("s_nop 7\n\ts_nop 7\n\ts_nop 7\n\ts_nop 7" : "+v"(d0), "+v"(d1));
}
// VALU write -> MFMA read of the same reg needs ~2 waits; 4 here.
static __device__ __forceinline__ void valu_fence4(int4v& f0, int4v& f1, int4v& f2, int4v& f3) {
    asm("s_nop 3" : "+v"(f0), "+v"(f1), "+v"(f2), "+v"(f3));
}
static __device__ __forceinline__ void valu_fence1(int4v& f0) {
    asm("s_nop 3" : "+v"(f0));
}

__global__ __launch_bounds__(512, 4) void mlp_mfma(
    const float* __restrict__ points,
    const unsigned char* __restrict__ ws,
    const float* __restrict__ bo,
    float* __restrict__ out, int n)
{
    __shared__ __align__(16) unsigned char lds[IMG_BYTES];

    // stage full weight image to LDS (53248 B = 3328 * 16; 512 threads)
    {
        const uint4* src = (const uint4*)ws;
        uint4* dst = (uint4*)lds;
#pragma unroll
        for (int i = 0; i < 6; ++i) {
            int idx = threadIdx.x + 512 * i;
            dst[idx] = src[idx];
        }
        if (threadIdx.x < 256) {
            int idx = 3072 + threadIdx.x;
            dst[idx] = src[idx];
        }
    }
    __syncthreads();

    const int lane = threadIdx.x & 63;
    const int wv = threadIdx.x >> 6;   // 0..7 (8 waves/block)
    const int p = lane & 31;
    const int h = lane >> 5;
    const int pt = (blockIdx.x * 8 + wv) * 32 + p;   // 32 points per wave
    const int pl = min(pt, n - 1);

    const half8* Wf = (const half8*)(lds + OFF_A);          // [l][t][s][lane]
    const half8* A0 = (const half8*)(lds + OFF_B);          // [t][lane]
    const floatx16* biasC = (const floatx16*)(lds + OFF_C); // [(l*2+h)*2+t]
    const floatx16* woC = (const floatx16*)(lds + OFF_D);   // [h*2+t]

    floatx16 acc[2];   // [mtile] — arch VGPRs via inline-asm MFMA
    int4v frv[4];      // packed activations, [kstep] = next B-frag

    // ---- layer 0 ----
    {
        int4v bv = {0, 0, 0, 0};
        if (h == 0) {
            bv[0] = pkrtz(points[3 * pl + 0], points[3 * pl + 1]);
            bv[1] = pkrtz(points[3 * pl + 2], 0.f);
        }
        valu_fence1(bv);   // VALU write -> MFMA read hazard
        floatx16 c0 = biasC[h * 2 + 0];   // l = 0
        floatx16 c1 = biasC[h * 2 + 1];
        __builtin_amdgcn_s_setprio(1);
        acc[0] = mfma_init(A0[lane], as_h8(bv), c0);
        acc[1] = mfma_init(A0[64 + lane], as_h8(bv), c1);
        __builtin_amdgcn_s_setprio(0);
        mfma_fence(acc[0], acc[1]);   // MFMA write -> VALU read hazard
    }

    // pack + lrelu -> frv (also the next layer's B-frags, exchange-free)
    auto packfr = [&]() {
#pragma unroll
        for (int t = 0; t < 2; ++t)
#pragma unroll
            for (int rp = 0; rp < 8; ++rp) {
                int v = pkrtz(acc[t][2 * rp], acc[t][2 * rp + 1]);
                int idx = 8 * t + rp;
                frv[idx >> 2][idx & 3] = lrelu2(v);
            }
    };
    packfr();

    // ---- 6 hidden layers ----
    for (int l = 0; l < N_HID; ++l) {
        const floatx16 c0 = biasC[((l + 1) * 2 + h) * 2 + 0];
        const floatx16 c1 = biasC[((l + 1) * 2 + h) * 2 + 1];
        const half8* wl = Wf + l * 512 + lane;  // + t*256 + s*64
        valu_fence4(frv[0], frv[1], frv[2], frv[3]);   // VALU write -> MFMA read
        __builtin_amdgcn_s_setprio(1);
        acc[0] = mfma_init(wl[0],   as_h8(frv[0]), c0);
        acc[1] = mfma_init(wl[256], as_h8(frv[0]), c1);
#pragma unroll
        for (int s = 1; s < 4; ++s) {
            mfma_acc(acc[0], wl[s * 64],       as_h8(frv[s]));
            mfma_acc(acc[1], wl[256 + s * 64], as_h8(frv[s]));
        }
        __builtin_amdgcn_s_setprio(0);
        mfma_fence(acc[0], acc[1]);   // MFMA write -> VALU read
        if (l < N_HID - 1) packfr();
    }

    // ---- output layer: fp32 lrelu + dot with wo (C-layout), cross-half reduce ----
    {
        floatx16 wo0 = woC[h * 2 + 0];
        floatx16 wo1 = woC[h * 2 + 1];
        float part = 0.f;
#pragma unroll
        for (int r = 0; r < 16; ++r) {
            float u;
            u = acc[0][r]; part = fmaf(fmaxf(u, 0.2f * u), wo0[r], part);
            u = acc[1][r]; part = fmaf(fmaxf(u, 0.2f * u), wo1[r], part);
        }
        part += __shfl_xor(part, 32);
        if (h == 0 && pt < n) out[pt] = part + bo[0];
    }
}

extern "C" void kernel_launch(void* const* d_in, const int* in_sizes, int n_in,
                              void* d_out, int out_size, void* d_ws, size_t ws_size,
                              hipStream_t stream) {
    const float* points = (const float*)d_in[0];
    const float* w0     = (const float*)d_in[1];
    const float* s0     = (const float*)d_in[2];
    const float* b0     = (const float*)d_in[3];
    const float* wh     = (const float*)d_in[4];
    const float* sh     = (const float*)d_in[5];
    const float* bh     = (const float*)d_in[6];
    const float* wo     = (const float*)d_in[7];
    const float* so     = (const float*)d_in[8];
    const float* bo     = (const float*)d_in[9];

    const int n = in_sizes[0] / 3;

    setup_weights<<<(SETUP_TOTAL + 255) / 256, 256, 0, stream>>>(
        w0, s0, b0, wh, sh, bh, wo, so, (unsigned char*)d_ws);

    const int grid = (n + 255) / 256;  // 256 points per block (8 waves x 32)
    mlp_mfma<<<grid, 512, 0, stream>>>(
        points, (const unsigned char*)d_ws, bo, (float*)d_out, n);
}

// Round 7
// 134.640 us; speedup vs baseline: 1.4894x; 1.0153x over previous
//
#include <hip/hip_runtime.h>

// ImplicitFunction MLP via fp16 MFMA (v_mfma_f32_32x32x16_f16), round 11.
// Round-11: round-7's two-stream pipeline, de-risked. Evidence recap:
//  - Every round shows dur ~= VALU-busy + MFMA-busy (sum, never max): the
//    pipes never overlap within a wave, at any occupancy (25%..50%).
//  - Best remains the 64-pt/wave r1 structure (57.4us): fixed per-wave costs
//    amortize over 2x points vs the 32-pt variants (62-64us).
//  - r7 (two-stream pipeline) failed ONLY via spill (WRITE_SIZE 241MB):
//    full unroll + (512,4)=128-reg cap. Live state needs ~155 regs.
// Changes vs r1 (the 57.4us best):
//  - Per layer: [MFMA stream0 || pack stream1] -> [MFMA stream1 || pack
//    stream0]. Each pack is data-independent of the MFMA cluster it overlaps.
//  - __launch_bounds__(512,3): 170-reg cap fits ~155 live regs, no spill.
//  - #pragma unroll 1 on the layer loop: keeps the scheduler's hoisting
//    window (and register pressure) small — r7's spill driver was unroll.
//  - Builtin MFMA (compiler handles MFMA<->VALU hazard nops; r9's asm NaN'd).
//
// Carried from r1: K-permuted weights (exchange-free layer transition), bias
// in MFMA C-operand, packed-fp16 lrelu, activations scaled 1/64, 64 pts/wave,
// fp32 epilogue dot, 512-thread blocks, 53248-B LDS image, setprio.
//
// Layouts (gfx950, 32x32x16):
//   A/B frag: lane (i=lane&31, h=lane>>5) holds k = 8h+j, j=0..7
//   C/D:      col n = lane&31, row m = (r&3) + 8*(r>>2) + 4h, r=0..15
//   k-slot:   feat(s,h,j) = 16s + 8*(j>>2) + 4h + (j&3)

typedef _Float16 half8 __attribute__((ext_vector_type(8)));
typedef _Float16 half2v __attribute__((ext_vector_type(2)));
typedef float floatx16 __attribute__((ext_vector_type(16)));
typedef int int4v __attribute__((ext_vector_type(4)));

#define N_HID 6
// ws / LDS byte offsets (single contiguous image, staged wholesale)
#define OFF_A 0        // hidden W frags [l:6][t:2][s:4][lane:64][j:8] fp16 = 49152
#define OFF_B 49152    // layer0 A frags [t:2][lane:64][j:8] fp16          = 2048
#define OFF_C 51200    // bias/64 fp32, C-layout [l:7][h:2][t:2][r:16]     = 1792
#define OFF_D 52992    // wo*so*64 fp32, C-layout [h:2][t:2][r:16]         = 256
#define IMG_BYTES 53248
#define SETUP_TOTAL (24576 + 1024 + 448 + 64)

__global__ __launch_bounds__(256) void setup_weights(
    const float* __restrict__ w0, const float* __restrict__ s0, const float* __restrict__ b0,
    const float* __restrict__ wh, const float* __restrict__ sh, const float* __restrict__ bh,
    const float* __restrict__ wo, const float* __restrict__ so,
    unsigned char* __restrict__ ws)
{
    int i = blockIdx.x * 256 + threadIdx.x;
    if (i < 24576) {
        // hidden W frags with K-permutation baked in:
        // A[m][kslot(s,h,j)] = wh[l][feat][m] * sh[l][m], feat = 16s+8*(j>>2)+4h+(j&3)
        int j = i & 7, lane = (i >> 3) & 63, s = (i >> 9) & 3, t = (i >> 11) & 1, l = i >> 12;
        int m = 32 * t + (lane & 31);
        int h = lane >> 5;
        int feat = 16 * s + 8 * (j >> 2) + 4 * h + (j & 3);
        ((_Float16*)(ws + OFF_A))[i] = (_Float16)(wh[(l * 64 + feat) * 64 + m] * sh[l * 64 + m]);
    } else if (i < 24576 + 1024) {
        // layer-0 A frags (standard k order; B built from raw points)
        int i2 = i - 24576;
        int j = i2 & 7, lane = (i2 >> 3) & 63, t = i2 >> 9;
        int m = 32 * t + (lane & 31);
        int k = 8 * (lane >> 5) + j;
        float v = (k < 3) ? w0[k * 64 + m] * s0[m] * 0.015625f : 0.f;
        ((_Float16*)(ws + OFF_B))[i2] = (_Float16)v;
    } else if (i < 24576 + 1024 + 448) {
        // biases/64 in C layout
        int i2 = i - 24576 - 1024;
        int r = i2 & 15, t = (i2 >> 4) & 1, h = (i2 >> 5) & 1, l = i2 >> 6;
        int feat = 32 * t + (r & 3) + 8 * ((r >> 2) & 3) + 4 * h;
        float bv = (l == 0) ? b0[feat] : bh[(l - 1) * 64 + feat];
        ((float*)(ws + OFF_C))[i2] = bv * 0.015625f;
    } else if (i < SETUP_TOTAL) {
        // wo*so*64 in C layout
        int i2 = i - 24576 - 1024 - 448;
        int r = i2 & 15, t = (i2 >> 4) & 1, h = i2 >> 5;
        int feat = 32 * t + (r & 3) + 8 * ((r >> 2) & 3) + 4 * h;
        ((float*)(ws + OFF_D))[i2] = wo[feat] * so[0] * 64.f;
    }
}

static __device__ __forceinline__ int pkrtz(float a, float b) {
    auto hh = __builtin_amdgcn_cvt_pkrtz(a, b);  // v2f16, RTZ pack
    int r;
    __builtin_memcpy(&r, &hh, 4);
    return r;
}

// packed-fp16 leaky relu on a pair: max(u, 0.2*u) -> v_pk_mul_f16 + v_pk_max_f16
static __device__ __forceinline__ int lrelu2(int v) {
    half2v u;
    __builtin_memcpy(&u, &v, 4);
    half2v w = u * (_Float16)0.2f;
    half2v r = __builtin_elementwise_max(u, w);
    int o;
    __builtin_memcpy(&o, &r, 4);
    return o;
}

static __device__ __forceinline__ half8 as_h8(int4v v) {
    half8 r;
    __builtin_memcpy(&r, &v, 16);
    return r;
}

static __device__ __forceinline__ floatx16 mfma16(half8 a, half8 b, floatx16 c) {
    return __builtin_amdgcn_mfma_f32_32x32x16_f16(a, b, c, 0, 0, 0);
}

// acc pair -> packed+lrelu B-frags (constant indices after inlining)
static __device__ __forceinline__ void packfr2(const floatx16 a[2], int4v f[4]) {
#pragma unroll
    for (int t = 0; t < 2; ++t)
#pragma unroll
        for (int rp = 0; rp < 8; ++rp) {
            int v = pkrtz(a[t][2 * rp], a[t][2 * rp + 1]);
            int idx = 8 * t + rp;
            f[idx >> 2][idx & 3] = lrelu2(v);
        }
}

__global__ __launch_bounds__(512, 3) void mlp_mfma(
    const float* __restrict__ points,
    const unsigned char* __restrict__ ws,
    const float* __restrict__ bo,
    float* __restrict__ out, int n)
{
    __shared__ __align__(16) unsigned char lds[IMG_BYTES];

    // stage full weight image to LDS (53248 B = 3328 * 16; 512 threads)
    {
        const uint4* src = (const uint4*)ws;
        uint4* dst = (uint4*)lds;
#pragma unroll
        for (int i = 0; i < 6; ++i) {
            int idx = threadIdx.x + 512 * i;
            dst[idx] = src[idx];
        }
        if (threadIdx.x < 256) {
            int idx = 3072 + threadIdx.x;
            dst[idx] = src[idx];
        }
    }
    __syncthreads();

    const int lane = threadIdx.x & 63;
    const int wv = threadIdx.x >> 6;   // 0..7 (8 waves/block)
    const int p = lane & 31;
    const int h = lane >> 5;
    const int base = (blockIdx.x * 8 + wv) * 64;
    const int pt0 = base + p, pt1 = base + 32 + p;
    const int pl0 = min(pt0, n - 1), pl1 = min(pt1, n - 1);

    const half8* Wf = (const half8*)(lds + OFF_A);          // [l][t][s][lane]
    const half8* A0 = (const half8*)(lds + OFF_B);          // [t][lane]
    const floatx16* biasC = (const floatx16*)(lds + OFF_C); // [(l*2+h)*2+t]
    const floatx16* woC = (const floatx16*)(lds + OFF_D);   // [h*2+t]

    floatx16 acc0[2], acc1[2];   // [mtile] per stream
    int4v frv0[4], frv1[4];      // packed activations per stream, [kstep]

    // ---- layer 0, both streams ----
    {
        int4v z4 = {0, 0, 0, 0};
        int4v b0v = z4, b1v = z4;
        if (h == 0) {
            b0v[0] = pkrtz(points[3 * pl0 + 0], points[3 * pl0 + 1]);
            b0v[1] = pkrtz(points[3 * pl0 + 2], 0.f);
            b1v[0] = pkrtz(points[3 * pl1 + 0], points[3 * pl1 + 1]);
            b1v[1] = pkrtz(points[3 * pl1 + 2], 0.f);
        }
        floatx16 c0 = biasC[h * 2 + 0];   // l = 0
        floatx16 c1 = biasC[h * 2 + 1];
        half8 a0 = A0[lane], a1 = A0[64 + lane];
        __builtin_amdgcn_s_setprio(1);
        acc0[0] = mfma16(a0, as_h8(b0v), c0);
        acc0[1] = mfma16(a1, as_h8(b0v), c1);
        acc1[0] = mfma16(a0, as_h8(b1v), c0);
        acc1[1] = mfma16(a1, as_h8(b1v), c1);
        __builtin_amdgcn_s_setprio(0);
    }

    // prologue: only stream0 packed; stream1's pack pipelines into the loop
    packfr2(acc0, frv0);

    // ---- 6 hidden layers, two-stream software pipeline ----
    // [MFMA0 || pack1(prev)] -> [MFMA1 || pack0(cur)]
#pragma unroll 1
    for (int l = 0; l < N_HID; ++l) {
        const half8* wl = Wf + l * 512 + lane;  // + t*256 + s*64
        floatx16 c0 = biasC[((l + 1) * 2 + h) * 2 + 0];
        floatx16 c1 = biasC[((l + 1) * 2 + h) * 2 + 1];

        // MFMA cluster, stream 0 (consumes frv0 = prev-layer activations)
        __builtin_amdgcn_s_setprio(1);
        acc0[0] = mfma16(wl[0],   as_h8(frv0[0]), c0);
        acc0[1] = mfma16(wl[256], as_h8(frv0[0]), c1);
#pragma unroll
        for (int s = 1; s < 4; ++s) {
            acc0[0] = mfma16(wl[s * 64],       as_h8(frv0[s]), acc0[0]);
            acc0[1] = mfma16(wl[256 + s * 64], as_h8(frv0[s]), acc0[1]);
        }
        __builtin_amdgcn_s_setprio(0);

        // pack stream 1 from PREVIOUS layer's acc1 — independent of MFMA0
        packfr2(acc1, frv1);

        // MFMA cluster, stream 1
        __builtin_amdgcn_s_setprio(1);
        acc1[0] = mfma16(wl[0],   as_h8(frv1[0]), c0);
        acc1[1] = mfma16(wl[256], as_h8(frv1[0]), c1);
#pragma unroll
        for (int s = 1; s < 4; ++s) {
            acc1[0] = mfma16(wl[s * 64],       as_h8(frv1[s]), acc1[0]);
            acc1[1] = mfma16(wl[256 + s * 64], as_h8(frv1[s]), acc1[1]);
        }
        __builtin_amdgcn_s_setprio(0);

        // pack stream 0 from THIS layer's acc0 — independent of MFMA1
        if (l < N_HID - 1) packfr2(acc0, frv0);
    }

    // ---- output layer: fp32 lrelu + dot with wo (C-layout), cross-half reduce ----
    {
        floatx16 wo0 = woC[h * 2 + 0];
        floatx16 wo1 = woC[h * 2 + 1];
        float part0 = 0.f, part1 = 0.f;
#pragma unroll
        for (int r = 0; r < 16; ++r) {
            float u;
            u = acc0[0][r]; part0 = fmaf(fmaxf(u, 0.2f * u), wo0[r], part0);
            u = acc0[1][r]; part0 = fmaf(fmaxf(u, 0.2f * u), wo1[r], part0);
            u = acc1[0][r]; part1 = fmaf(fmaxf(u, 0.2f * u), wo0[r], part1);
            u = acc1[1][r]; part1 = fmaf(fmaxf(u, 0.2f * u), wo1[r], part1);
        }
        part0 += __shfl_xor(part0, 32);
        part1 += __shfl_xor(part1, 32);
        const float bov = bo[0];
        if (h == 0) {
            if (pt0 < n) out[pt0] = part0 + bov;
            if (pt1 < n) out[pt1] = part1 + bov;
        }
    }
}

extern "C" void kernel_launch(void* const* d_in, const int* in_sizes, int n_in,
                              void* d_out, int out_size, void* d_ws, size_t ws_size,
                              hipStream_t stream) {
    const float* points = (const float*)d_in[0];
    const float* w0     = (const float*)d_in[1];
    const float* s0     = (const float*)d_in[2];
    const float* b0     = (const float*)d_in[3];
    const float* wh     = (const float*)d_in[4];
    const float* sh     = (const float*)d_in[5];
    const float* bh     = (const float*)d_in[6];
    const float* wo     = (const float*)d_in[7];
    const float* so     = (const float*)d_in[8];
    const float* bo     = (const float*)d_in[9];

    const int n = in_sizes[0] / 3;

    setup_weights<<<(SETUP_TOTAL + 255) / 256, 256, 0, stream>>>(
        w0, s0, b0, wh, sh, bh, wo, so, (unsigned char*)d_ws);

    const int grid = (n + 511) / 512;  // 512 points per block (8 waves x 64)
    mlp_mfma<<<grid, 512, 0, stream>>>(
        points, (const unsigned char*)d_ws, bo, (float*)d_out, n);
}

// Round 8
// 131.105 us; speedup vs baseline: 1.5295x; 1.0270x over previous
//
#include <hip/hip_runtime.h>

// ImplicitFunction MLP via fp16 MFMA (v_mfma_f32_32x32x16_f16), round 12.
// Round-12: compile-time MFMA/VALU interleave via sched_group_barrier.
// Diagnosis across r1..r11: dur ~= MFMA-busy + VALU-busy (sum, never max)
// at every occupancy; source-level phase reordering (r7, r11) didn't help.
// Mechanism: wave issue is IN-ORDER — 8 contiguous MFMAs block the wave's
// issue slot, so pack VALU behind them never issues under the matrix pipe;
// and identical waves stay phase-locked, so cross-wave overlap never
// materializes either. The fix must be in the EMITTED instruction order:
//  - Loop body made branch-free (both packs unguarded, layer 5 peeled) so
//    each layer is ONE scheduling region: 16 MFMA + 96 pack-VALU.
//  - 16x { sched_group_barrier(MFMA,1); sched_group_barrier(VALU,6) }:
//    data deps then force cluster0-MFMA x pack1-VALU, cluster1 x pack0.
//    (1 MFMA ~ 8 pipe cy ~ 6 wave VALU inst.)
//  - setprio removed (no contiguous clusters remain; measured ~0 anyway).
//
// Carried from r11: two 32-pt streams per wave (64 pts/wave), K-permuted
// weights (exchange-free layer transition), bias in MFMA C-operand,
// packed-fp16 lrelu, activations scaled 1/64, fp32 epilogue dot,
// 512-thread blocks, 53248-B LDS image, __launch_bounds__(512,3),
// #pragma unroll 1 on the layer loop (r7's spill driver was full unroll).
//
// Layouts (gfx950, 32x32x16):
//   A/B frag: lane (i=lane&31, h=lane>>5) holds k = 8h+j, j=0..7
//   C/D:      col n = lane&31, row m = (r&3) + 8*(r>>2) + 4h, r=0..15
//   k-slot:   feat(s,h,j) = 16s + 8*(j>>2) + 4h + (j&3)

typedef _Float16 half8 __attribute__((ext_vector_type(8)));
typedef _Float16 half2v __attribute__((ext_vector_type(2)));
typedef float floatx16 __attribute__((ext_vector_type(16)));
typedef int int4v __attribute__((ext_vector_type(4)));

#define N_HID 6
// ws / LDS byte offsets (single contiguous image, staged wholesale)
#define OFF_A 0        // hidden W frags [l:6][t:2][s:4][lane:64][j:8] fp16 = 49152
#define OFF_B 49152    // layer0 A frags [t:2][lane:64][j:8] fp16          = 2048
#define OFF_C 51200    // bias/64 fp32, C-layout [l:7][h:2][t:2][r:16]     = 1792
#define OFF_D 52992    // wo*so*64 fp32, C-layout [h:2][t:2][r:16]         = 256
#define IMG_BYTES 53248
#define SETUP_TOTAL (24576 + 1024 + 448 + 64)

__global__ __launch_bounds__(256) void setup_weights(
    const float* __restrict__ w0, const float* __restrict__ s0, const float* __restrict__ b0,
    const float* __restrict__ wh, const float* __restrict__ sh, const float* __restrict__ bh,
    const float* __restrict__ wo, const float* __restrict__ so,
    unsigned char* __restrict__ ws)
{
    int i = blockIdx.x * 256 + threadIdx.x;
    if (i < 24576) {
        // hidden W frags with K-permutation baked in:
        // A[m][kslot(s,h,j)] = wh[l][feat][m] * sh[l][m], feat = 16s+8*(j>>2)+4h+(j&3)
        int j = i & 7, lane = (i >> 3) & 63, s = (i >> 9) & 3, t = (i >> 11) & 1, l = i >> 12;
        int m = 32 * t + (lane & 31);
        int h = lane >> 5;
        int feat = 16 * s + 8 * (j >> 2) + 4 * h + (j & 3);
        ((_Float16*)(ws + OFF_A))[i] = (_Float16)(wh[(l * 64 + feat) * 64 + m] * sh[l * 64 + m]);
    } else if (i < 24576 + 1024) {
        // layer-0 A frags (standard k order; B built from raw points)
        int i2 = i - 24576;
        int j = i2 & 7, lane = (i2 >> 3) & 63, t = i2 >> 9;
        int m = 32 * t + (lane & 31);
        int k = 8 * (lane >> 5) + j;
        float v = (k < 3) ? w0[k * 64 + m] * s0[m] * 0.015625f : 0.f;
        ((_Float16*)(ws + OFF_B))[i2] = (_Float16)v;
    } else if (i < 24576 + 1024 + 448) {
        // biases/64 in C layout
        int i2 = i - 24576 - 1024;
        int r = i2 & 15, t = (i2 >> 4) & 1, h = (i2 >> 5) & 1, l = i2 >> 6;
        int feat = 32 * t + (r & 3) + 8 * ((r >> 2) & 3) + 4 * h;
        float bv = (l == 0) ? b0[feat] : bh[(l - 1) * 64 + feat];
        ((float*)(ws + OFF_C))[i2] = bv * 0.015625f;
    } else if (i < SETUP_TOTAL) {
        // wo*so*64 in C layout
        int i2 = i - 24576 - 1024 - 448;
        int r = i2 & 15, t = (i2 >> 4) & 1, h = i2 >> 5;
        int feat = 32 * t + (r & 3) + 8 * ((r >> 2) & 3) + 4 * h;
        ((float*)(ws + OFF_D))[i2] = wo[feat] * so[0] * 64.f;
    }
}

static __device__ __forceinline__ int pkrtz(float a, float b) {
    auto hh = __builtin_amdgcn_cvt_pkrtz(a, b);  // v2f16, RTZ pack
    int r;
    __builtin_memcpy(&r, &hh, 4);
    return r;
}

// packed-fp16 leaky relu on a pair: max(u, 0.2*u) -> v_pk_mul_f16 + v_pk_max_f16
static __device__ __forceinline__ int lrelu2(int v) {
    half2v u;
    __builtin_memcpy(&u, &v, 4);
    half2v w = u * (_Float16)0.2f;
    half2v r = __builtin_elementwise_max(u, w);
    int o;
    __builtin_memcpy(&o, &r, 4);
    return o;
}

static __device__ __forceinline__ half8 as_h8(int4v v) {
    half8 r;
    __builtin_memcpy(&r, &v, 16);
    return r;
}

static __device__ __forceinline__ floatx16 mfma16(half8 a, half8 b, floatx16 c) {
    return __builtin_amdgcn_mfma_f32_32x32x16_f16(a, b, c, 0, 0, 0);
}

// acc pair -> packed+lrelu B-frags (constant indices after inlining): 48 VALU
static __device__ __forceinline__ void packfr2(const floatx16 a[2], int4v f[4]) {
#pragma unroll
    for (int t = 0; t < 2; ++t)
#pragma unroll
        for (int rp = 0; rp < 8; ++rp) {
            int v = pkrtz(a[t][2 * rp], a[t][2 * rp + 1]);
            int idx = 8 * t + rp;
            f[idx >> 2][idx & 3] = lrelu2(v);
        }
}

// n units of {1 MFMA, 6 VALU} — compile-time interleave directive
static __device__ __forceinline__ void interleave_mfma_valu(int nunits) {
    // callers pass a compile-time constant; loop fully unrolls
#pragma unroll
    for (int u = 0; u < 16; ++u) {
        if (u < nunits) {
            __builtin_amdgcn_sched_group_barrier(0x008, 1, 0);  // 1 MFMA
            __builtin_amdgcn_sched_group_barrier(0x002, 6, 0);  // 6 VALU
        }
    }
}

__global__ __launch_bounds__(512, 3) void mlp_mfma(
    const float* __restrict__ points,
    const unsigned char* __restrict__ ws,
    const float* __restrict__ bo,
    float* __restrict__ out, int n)
{
    __shared__ __align__(16) unsigned char lds[IMG_BYTES];

    // stage full weight image to LDS (53248 B = 3328 * 16; 512 threads)
    {
        const uint4* src = (const uint4*)ws;
        uint4* dst = (uint4*)lds;
#pragma unroll
        for (int i = 0; i < 6; ++i) {
            int idx = threadIdx.x + 512 * i;
            dst[idx] = src[idx];
        }
        if (threadIdx.x < 256) {
            int idx = 3072 + threadIdx.x;
            dst[idx] = src[idx];
        }
    }
    __syncthreads();

    const int lane = threadIdx.x & 63;
    const int wv = threadIdx.x >> 6;   // 0..7 (8 waves/block)
    const int p = lane & 31;
    const int h = lane >> 5;
    const int base = (blockIdx.x * 8 + wv) * 64;
    const int pt0 = base + p, pt1 = base + 32 + p;
    const int pl0 = min(pt0, n - 1), pl1 = min(pt1, n - 1);

    const half8* Wf = (const half8*)(lds + OFF_A);          // [l][t][s][lane]
    const half8* A0 = (const half8*)(lds + OFF_B);          // [t][lane]
    const floatx16* biasC = (const floatx16*)(lds + OFF_C); // [(l*2+h)*2+t]
    const floatx16* woC = (const floatx16*)(lds + OFF_D);   // [h*2+t]

    floatx16 acc0[2], acc1[2];   // [mtile] per stream
    int4v frv0[4], frv1[4];      // packed activations per stream, [kstep]

    // ---- layer 0, both streams ----
    {
        int4v z4 = {0, 0, 0, 0};
        int4v b0v = z4, b1v = z4;
        if (h == 0) {
            b0v[0] = pkrtz(points[3 * pl0 + 0], points[3 * pl0 + 1]);
            b0v[1] = pkrtz(points[3 * pl0 + 2], 0.f);
            b1v[0] = pkrtz(points[3 * pl1 + 0], points[3 * pl1 + 1]);
            b1v[1] = pkrtz(points[3 * pl1 + 2], 0.f);
        }
        floatx16 c0 = biasC[h * 2 + 0];   // l = 0
        floatx16 c1 = biasC[h * 2 + 1];
        half8 a0 = A0[lane], a1 = A0[64 + lane];
        acc0[0] = mfma16(a0, as_h8(b0v), c0);
        acc0[1] = mfma16(a1, as_h8(b0v), c1);
        acc1[0] = mfma16(a0, as_h8(b1v), c0);
        acc1[1] = mfma16(a1, as_h8(b1v), c1);
    }

    // prologue: only stream0 packed; stream1's pack pipelines into the loop
    packfr2(acc0, frv0);

    // ---- hidden layers 0..4: branch-free body = one scheduling region ----
    // deps force: cluster0-MFMA x pack1-VALU, then cluster1-MFMA x pack0-VALU
#pragma unroll 1
    for (int l = 0; l < N_HID - 1; ++l) {
        const half8* wl = Wf + l * 512 + lane;  // + t*256 + s*64
        floatx16 c0 = biasC[((l + 1) * 2 + h) * 2 + 0];
        floatx16 c1 = biasC[((l + 1) * 2 + h) * 2 + 1];

        // MFMA cluster, stream 0 (consumes frv0 = prev-layer activations)
        acc0[0] = mfma16(wl[0],   as_h8(frv0[0]), c0);
        acc0[1] = mfma16(wl[256], as_h8(frv0[0]), c1);
#pragma unroll
        for (int s = 1; s < 4; ++s) {
            acc0[0] = mfma16(wl[s * 64],       as_h8(frv0[s]), acc0[0]);
            acc0[1] = mfma16(wl[256 + s * 64], as_h8(frv0[s]), acc0[1]);
        }

        // pack stream 1 from PREVIOUS layer's acc1 — independent of cluster0
        packfr2(acc1, frv1);

        // MFMA cluster, stream 1
        acc1[0] = mfma16(wl[0],   as_h8(frv1[0]), c0);
        acc1[1] = mfma16(wl[256], as_h8(frv1[0]), c1);
#pragma unroll
        for (int s = 1; s < 4; ++s) {
            acc1[0] = mfma16(wl[s * 64],       as_h8(frv1[s]), acc1[0]);
            acc1[1] = mfma16(wl[256 + s * 64], as_h8(frv1[s]), acc1[1]);
        }

        // pack stream 0 from THIS layer's acc0 — independent of cluster1
        packfr2(acc0, frv0);

        // 16 MFMA + 96 pack-VALU in this region -> 16 x {1 MFMA, 6 VALU}
        interleave_mfma_valu(16);
    }

    // ---- layer 5 (peeled: no pack0 afterwards) ----
    {
        const half8* wl = Wf + (N_HID - 1) * 512 + lane;
        floatx16 c0 = biasC[(N_HID * 2 + h) * 2 + 0];
        floatx16 c1 = biasC[(N_HID * 2 + h) * 2 + 1];

        acc0[0] = mfma16(wl[0],   as_h8(frv0[0]), c0);
        acc0[1] = mfma16(wl[256], as_h8(frv0[0]), c1);
#pragma unroll
        for (int s = 1; s < 4; ++s) {
            acc0[0] = mfma16(wl[s * 64],       as_h8(frv0[s]), acc0[0]);
            acc0[1] = mfma16(wl[256 + s * 64], as_h8(frv0[s]), acc0[1]);
        }

        packfr2(acc1, frv1);   // feeds cluster1 below

        interleave_mfma_valu(8);   // 8 MFMA + 48 VALU in-flight so far

        acc1[0] = mfma16(wl[0],   as_h8(frv1[0]), c0);
        acc1[1] = mfma16(wl[256], as_h8(frv1[0]), c1);
#pragma unroll
        for (int s = 1; s < 4; ++s) {
            acc1[0] = mfma16(wl[s * 64],       as_h8(frv1[s]), acc1[0]);
            acc1[1] = mfma16(wl[256 + s * 64], as_h8(frv1[s]), acc1[1]);
        }
    }

    // ---- output layer: fp32 lrelu + dot with wo (C-layout), cross-half reduce ----
    {
        floatx16 wo0 = woC[h * 2 + 0];
        floatx16 wo1 = woC[h * 2 + 1];
        float part0 = 0.f, part1 = 0.f;
#pragma unroll
        for (int r = 0; r < 16; ++r) {
            float u;
            u = acc0[0][r]; part0 = fmaf(fmaxf(u, 0.2f * u), wo0[r], part0);
            u = acc0[1][r]; part0 = fmaf(fmaxf(u, 0.2f * u), wo1[r], part0);
            u = acc1[0][r]; part1 = fmaf(fmaxf(u, 0.2f * u), wo0[r], part1);
            u = acc1[1][r]; part1 = fmaf(fmaxf(u, 0.2f * u), wo1[r], part1);
        }
        part0 += __shfl_xor(part0, 32);
        part1 += __shfl_xor(part1, 32);
        const float bov = bo[0];
        if (h == 0) {
            if (pt0 < n) out[pt0] = part0 + bov;
            if (pt1 < n) out[pt1] = part1 + bov;
        }
    }
}

extern "C" void kernel_launch(void* const* d_in, const int* in_sizes, int n_in,
                              void* d_out, int out_size, void* d_ws, size_t ws_size,
                              hipStream_t stream) {
    const float* points = (const float*)d_in[0];
    const float* w0     = (const float*)d_in[1];
    const float* s0     = (const float*)d_in[2];
    const float* b0     = (const float*)d_in[3];
    const float* wh     = (const float*)d_in[4];
    const float* sh     = (const float*)d_in[5];
    const float* bh     = (const float*)d_in[6];
    const float* wo     = (const float*)d_in[7];
    const float* so     = (const float*)d_in[8];
    const float* bo     = (const float*)d_in[9];

    const int n = in_sizes[0] / 3;

    setup_weights<<<(SETUP_TOTAL + 255) / 256, 256, 0, stream>>>(
        w0, s0, b0, wh, sh, bh, wo, so, (unsigned char*)d_ws);

    const int grid = (n + 511) / 512;  // 512 points per block (8 waves x 64)
    mlp_mfma<<<grid, 512, 0, stream>>>(
        points, (const unsigned char*)d_ws, bo, (float*)d_out, n);
}